// Round 2
// baseline (391.470 us; speedup 1.0000x reference)
//
#include <hip/hip_runtime.h>
#include <hip/hip_bf16.h>
#include <cstdint>
#include <cstddef>

// ---------------------------------------------------------------------------
// Fully-fused MixedRQCouplingTransform:
//   per 64-row block: build netin (cos/sin/ir/ctx) in LDS -> L1 -> L2 -> L3
//   (two 512-col passes) -> RQ-spline, all in one kernel. Weights (1.7MB bf16,
//   L2-resident) are consumed as MFMA B-fragments directly from global.
//   h1/h2/params never touch HBM.
// W3/b3 column-permuted at prep: 16 param slots per feature (64 x 16 = 1024).
// LDS rows XOR-swizzled (16B slots, ((r^(r>>3))&7)<<4) for conflict-free
// ds_read_b128 fragment reads at 1024B row stride.
// ---------------------------------------------------------------------------

typedef float  f32x4 __attribute__((ext_vector_type(4)));
typedef short  s16x8 __attribute__((ext_vector_type(8)));

__device__ __forceinline__ void mfma16(f32x4& acc, s16x8 a, s16x8 b) {
    asm volatile("v_mfma_f32_16x16x32_bf16 %0, %1, %2, %0" : "+v"(acc) : "v"(a), "v"(b));
}
__device__ __forceinline__ float bf2f(short s) {
    union { unsigned u; float f; } v; v.u = ((unsigned)(unsigned short)s) << 16; return v.f;
}
__device__ __forceinline__ short f2bf(float f) {
    __hip_bfloat16 h = __float2bfloat16(f); return *(short*)&h;
}
__device__ __forceinline__ int swz(int row) { return ((row ^ (row >> 3)) & 7) << 4; }

// ---------------- weight prep: bf16 transpose (+ W3/b3 16-pad permute) -----

__global__ void prep_weights_kernel(const float* __restrict__ W1,
                                    const float* __restrict__ W2,
                                    const float* __restrict__ W3,
                                    const float* __restrict__ b3,
                                    __hip_bfloat16* __restrict__ W1T,
                                    __hip_bfloat16* __restrict__ W2T,
                                    __hip_bfloat16* __restrict__ W3T,
                                    float* __restrict__ b3p)
{
    const int T1 = 512 * 192, T2 = 512 * 512, T3 = 1024 * 512;
    const int total = T1 + T2 + T3 + 1024;
    for (int t = blockIdx.x * blockDim.x + threadIdx.x; t < total;
         t += gridDim.x * blockDim.x) {
        if (t < T1) {
            int nn = t / 192, k = t % 192;
            float v = (k < 160) ? W1[(size_t)k * 512 + nn] : 0.f;
            W1T[t] = __float2bfloat16(v);
        } else if (t < T1 + T2) {
            int u = t - T1;
            int nn = u / 512, k = u % 512;
            W2T[u] = __float2bfloat16(W2[(size_t)k * 512 + nn]);
        } else if (t < T1 + T2 + T3) {
            int u = t - T1 - T2;
            int c = u / 512, k = u % 512;
            int f = c >> 4, p = c & 15;
            float v = 0.f;
            if (f < 32) { if (p < 15) v = W3[(size_t)k * 992 + f * 15 + p]; }
            else        {              v = W3[(size_t)k * 992 + 480 + (f - 32) * 16 + p]; }
            W3T[u] = __float2bfloat16(v);
        } else {
            int c = t - T1 - T2 - T3;
            int f = c >> 4, p = c & 15;
            float v = 0.f;
            if (f < 32) { if (p < 15) v = b3[f * 15 + p]; }
            else        {              v = b3[480 + (f - 32) * 16 + p]; }
            b3p[c] = v;
        }
    }
}

// ---------------- per-wave 64x64 GEMM chunk: LDS A (swizzled) x global B ---

template<int K, bool RELU>
__device__ __forceinline__ void layer_gemm(
    const char* Alds, int lda,                 // A in LDS, bytes per row
    const short* __restrict__ Bg,              // weights [cols][K], k-contig
    const float* __restrict__ bias, int bias0,
    int col0,                                  // this wave's 64-col base (local)
    char* Hdst, int ldh,                       // dst in LDS (swizzled rows)
    int lane)
{
    const int fr = lane & 15, fq = lane >> 4;
    f32x4 acc[4][4] = {};
    const short* brow[4];
#pragma unroll
    for (int n = 0; n < 4; ++n)
        brow[n] = Bg + (size_t)(col0 + n * 16 + fr) * K;
    const char* arow[4]; int asw[4];
#pragma unroll
    for (int m = 0; m < 4; ++m) {
        const int r = m * 16 + fr;
        arow[m] = Alds + r * lda;
        asw[m]  = swz(r);
    }
#pragma unroll 4
    for (int kk = 0; kk < K / 32; ++kk) {
        s16x8 a[4], b[4];
#pragma unroll
        for (int n = 0; n < 4; ++n)
            b[n] = *(const s16x8*)(brow[n] + kk * 32 + fq * 8);
#pragma unroll
        for (int m = 0; m < 4; ++m)
            a[m] = *(const s16x8*)(arow[m] + ((kk * 64 + fq * 16) ^ asw[m]));
#pragma unroll
        for (int m = 0; m < 4; ++m)
#pragma unroll
            for (int n = 0; n < 4; ++n)
                mfma16(acc[m][n], a[m], b[n]);
    }
    // epilogue: bias(+relu) -> bf16 -> LDS (swizzled). C/D: col=lane&15, row=fq*4+r
#pragma unroll
    for (int n = 0; n < 4; ++n) {
        const int col = col0 + n * 16 + fr;
        const float bv = bias[bias0 + col];
#pragma unroll
        for (int m = 0; m < 4; ++m) {
#pragma unroll
            for (int r = 0; r < 4; ++r) {
                const int row = m * 16 + fq * 4 + r;
                float v = acc[m][n][r] + bv;
                if (RELU) v = fmaxf(v, 0.f);
                *(short*)(Hdst + row * ldh + ((col * 2) ^ swz(row))) = f2bf(v);
            }
        }
    }
}

// ---------------- RQ spline for one feature (lane-local) -------------------
// CH=0: circular tc (left=-pi, ud wraps); CH=1: tr (left=-5, tail identity).

template<int CH>
__device__ __forceinline__ float spline_eval(s16x8 p0, s16x8 p1,
                                             const float* __restrict__ inputs,
                                             float* __restrict__ out,
                                             size_t grow, int f)
{
    const float PI_F  = 3.14159265358979323846f;
    const float left  = (CH == 0) ? -PI_F : -5.0f;
    const float right = -left;
    const float SCALE = 0.04419417382415922f;  // 1/sqrt(512)

    float uw[5], uh[5], ud[6];
    uw[0] = bf2f(p0[0]) * SCALE; uw[1] = bf2f(p0[1]) * SCALE; uw[2] = bf2f(p0[2]) * SCALE;
    uw[3] = bf2f(p0[3]) * SCALE; uw[4] = bf2f(p0[4]) * SCALE;
    uh[0] = bf2f(p0[5]) * SCALE; uh[1] = bf2f(p0[6]) * SCALE; uh[2] = bf2f(p0[7]) * SCALE;
    uh[3] = bf2f(p1[0]) * SCALE; uh[4] = bf2f(p1[1]) * SCALE;
    ud[0] = bf2f(p1[2]); ud[1] = bf2f(p1[3]); ud[2] = bf2f(p1[4]);
    ud[3] = bf2f(p1[5]); ud[4] = bf2f(p1[6]);
    ud[5] = (CH == 0) ? ud[0] : bf2f(p1[7]);

    const int xcol = (CH == 0) ? 32 + f : 96 + f;
    const int ccol = (CH == 0) ? f : 64 + f;
    const float x = inputs[grow * 128 + xcol];

    float mx = uw[0];
#pragma unroll
    for (int i = 1; i < 5; ++i) mx = fmaxf(mx, uw[i]);
    float e[5], s = 0.f;
#pragma unroll
    for (int i = 0; i < 5; ++i) { e[i] = __expf(uw[i] - mx); s += e[i]; }
    const float inv_s = 1.f / s;
    float cw[6];
    cw[0] = left;
    {
        float a = 0.f;
#pragma unroll
        for (int i = 0; i < 5; ++i) {
            a += 0.001f + 0.995f * (e[i] * inv_s);
            cw[i + 1] = left + (right - left) * a;
        }
    }
    cw[5] = right;

    float mh = uh[0];
#pragma unroll
    for (int i = 1; i < 5; ++i) mh = fmaxf(mh, uh[i]);
    float eh[5], sh = 0.f;
#pragma unroll
    for (int i = 0; i < 5; ++i) { eh[i] = __expf(uh[i] - mh); sh += eh[i]; }
    const float inv_sh = 1.f / sh;
    float ch[6];
    ch[0] = left;
    {
        float a = 0.f;
#pragma unroll
        for (int i = 0; i < 5; ++i) {
            a += 0.001f + 0.995f * (eh[i] * inv_sh);
            ch[i + 1] = left + (right - left) * a;
        }
    }
    ch[5] = right;

    float d[6];
#pragma unroll
    for (int i = 0; i < 6; ++i) {
        float u  = ud[i];
        d[i] = 0.001f + fmaxf(u, 0.f) + log1pf(__expf(-fabsf(u)));
    }

    const float xc = fminf(fmaxf(x, left), right);
    int b = 0;
#pragma unroll
    for (int i = 1; i <= 5; ++i) b += (xc >= cw[i]) ? 1 : 0;
    b = (b > 4) ? 4 : b;

    float l_cw = cw[0], r_cw = cw[1], l_ch = ch[0], r_ch = ch[1], dk = d[0], dk1 = d[1];
#pragma unroll
    for (int i = 1; i < 5; ++i) {
        if (b == i) {
            l_cw = cw[i]; r_cw = cw[i + 1];
            l_ch = ch[i]; r_ch = ch[i + 1];
            dk   = d[i];  dk1  = d[i + 1];
        }
    }

    const float iw  = r_cw - l_cw;
    const float ih  = r_ch - l_ch;
    const float del = ih / iw;
    const float th  = (xc - l_cw) / iw;
    const float omt = 1.f - th;
    const float num = ih * (del * th * th + dk * th * omt);
    const float den = del + (dk + dk1 - 2.f * del) * th * omt;
    float y = l_ch + num / den;
    const float dnum = del * del * (dk1 * th * th + 2.f * del * th * omt + dk * omt * omt);
    float lad = __logf(dnum) - 2.f * __logf(den);

    if (CH == 1) {
        const bool inside = (x >= -5.0f) && (x <= 5.0f);
        if (!inside) { y = x; lad = 0.f; }
    }

    out[grow * 128 + ccol] = inputs[grow * 128 + ccol];  // identity half
    out[grow * 128 + xcol] = y;
    return lad;
}

// ---------------- fused kernel --------------------------------------------

__global__ __launch_bounds__(512)
void fused_mlp_spline(const float* __restrict__ inputs, const float* __restrict__ context,
                      const short* __restrict__ W1T, const float* __restrict__ b1,
                      const short* __restrict__ W2T, const float* __restrict__ b2,
                      const short* __restrict__ W3T, const float* __restrict__ b3p,
                      float* __restrict__ out, int Nrows)
{
    __shared__ __align__(16) char smem[155648];           // 152KB
    char* A1  = smem;                                     // [64][192] bf16 (lda 384)
    char* H1  = smem + 24576;                             // [64][512] (ldh 1024)
    char* H2  = smem + 90112;                             // [64][512]
    char* PAR = smem;                                     // [64][512] overlaps dead A1+H1

    const int tid  = threadIdx.x;
    const int w    = tid >> 6;
    const int lane = tid & 63;
    const int row0 = blockIdx.x * 64;

    // ---- build netin = [cos(ic), sin(ic), ir, ctx, 0-pad] into A1 ----
    {
        const int r  = tid >> 3;
        const int cb = (tid & 7) * 24;
        const float* inr = inputs  + (size_t)(row0 + r) * 128;
        const float* ctr = context + (size_t)(row0 + r) * 64;
        const int sw = swz(r);
#pragma unroll
        for (int j = 0; j < 24; ++j) {
            const int c = cb + j;
            float v;
            if      (c < 32)  v = cosf(inr[c]);
            else if (c < 64)  v = sinf(inr[c - 32]);
            else if (c < 96)  v = inr[c];
            else if (c < 160) v = ctr[c - 96];
            else              v = 0.f;
            *(short*)(A1 + r * 384 + ((c * 2) ^ sw)) = f2bf(v);
        }
    }
    __syncthreads();
    layer_gemm<192, true >(A1, 384,  W1T, b1, 0,   w * 64, H1, 1024, lane);
    __syncthreads();
    layer_gemm<512, true >(H1, 1024, W2T, b2, 0,   w * 64, H2, 1024, lane);
    __syncthreads();

    float lad_acc[4];

    // ---- L3 pass 1: param cols 0..511 (tc features 0..31) + spline ----
    layer_gemm<512, false>(H2, 1024, W3T, b3p, 0,  w * 64, PAR, 1024, lane);
    __syncthreads();
#pragma unroll
    for (int it = 0; it < 4; ++it) {
        const int row = w * 8 + it * 2 + (lane >> 5);
        const int f   = lane & 31;
        const char* base = PAR + row * 1024;
        const int sw = swz(row);
        s16x8 p0 = *(const s16x8*)(base + ((f * 32)      ^ sw));
        s16x8 p1 = *(const s16x8*)(base + ((f * 32 + 16) ^ sw));
        lad_acc[it] = spline_eval<0>(p0, p1, inputs, out, (size_t)row0 + row, f);
    }
    __syncthreads();

    // ---- L3 pass 2: param cols 512..1023 (tr features 32..63) + spline ----
    layer_gemm<512, false>(H2, 1024, W3T + (size_t)512 * 512, b3p, 512, w * 64, PAR, 1024, lane);
    __syncthreads();
#pragma unroll
    for (int it = 0; it < 4; ++it) {
        const int row = w * 8 + it * 2 + (lane >> 5);
        const int f   = lane & 31;
        const char* base = PAR + row * 1024;
        const int sw = swz(row);
        s16x8 p0 = *(const s16x8*)(base + ((f * 32)      ^ sw));
        s16x8 p1 = *(const s16x8*)(base + ((f * 32 + 16) ^ sw));
        float lad = lad_acc[it] + spline_eval<1>(p0, p1, inputs, out, (size_t)row0 + row, f);
#pragma unroll
        for (int o = 16; o > 0; o >>= 1) lad += __shfl_xor(lad, o, 64);
        if ((lane & 31) == 0) out[(size_t)Nrows * 128 + row0 + row] = lad;
    }
}

// ---------------- launcher -------------------------------------------------

extern "C" void kernel_launch(void* const* d_in, const int* in_sizes, int n_in,
                              void* d_out, int out_size, void* d_ws, size_t ws_size,
                              hipStream_t stream)
{
    const float* inputs  = (const float*)d_in[0];
    const float* context = (const float*)d_in[1];
    const float* W1 = (const float*)d_in[2];
    const float* b1 = (const float*)d_in[3];
    const float* W2 = (const float*)d_in[4];
    const float* b2 = (const float*)d_in[5];
    const float* W3 = (const float*)d_in[6];
    const float* b3 = (const float*)d_in[7];
    float* out = (float*)d_out;

    const int Nrows = in_sizes[0] / 128;  // 65536

    char* ws = (char*)d_ws;
    __hip_bfloat16* W1T = (__hip_bfloat16*)(ws);                      // 512*192*2
    __hip_bfloat16* W2T = (__hip_bfloat16*)(ws + 196608);             // 512*512*2
    __hip_bfloat16* W3T = (__hip_bfloat16*)(ws + 720896);             // 1024*512*2
    float*          b3p = (float*)         (ws + 1769472);            // 1024*4

    prep_weights_kernel<<<2048, 256, 0, stream>>>(W1, W2, W3, b3, W1T, W2T, W3T, b3p);

    fused_mlp_spline<<<Nrows / 64, 512, 0, stream>>>(
        inputs, context,
        (const short*)W1T, b1, (const short*)W2T, b2, (const short*)W3T, b3p,
        out, Nrows);
}